// Round 4
// baseline (178.145 us; speedup 1.0000x reference)
//
#include <hip/hip_runtime.h>
#include <hip/hip_bf16.h>

// ---------------------------------------------------------------------------
// Round 4: same verified math as round 3 (passed, absmax 0.0625), restructured
// for memory behavior:
//  * Block = 4 waves, SAME phase, 8 consecutive (z,y) rows (2 rows/wave).
//  * Conv weights staged in LDS in 2 chunks of 48KB (taps 0-3, 4-7); A-frags
//    come from ds_read_b128 and are read once per block from L2 (4x less
//    global weight traffic than r3, 8x less than per-wave streaming).
//  * x relayout [row][cb][pos][16ch] so each B-frag load is one contiguous
//    1KB wave transaction (was 16B/lane at 128B stride = 50% line util).
//  * bid = p*128 + rowGroup => XCD = rowGroup%8: all 8 phases of a row-group
//    on one XCD (x reads shared in L2; stride-2 cp stores merge).
// Epilogue (BN1/ReLU/pack, fixed half-wave shuffle combine, BN2/ReLU store)
// is identical to round 3's verified code.
// ---------------------------------------------------------------------------

typedef __bf16 bf16x8 __attribute__((ext_vector_type(8)));
typedef float f32x16 __attribute__((ext_vector_type(16)));

__device__ inline unsigned short f2bf(float f) {
  unsigned int u = __float_as_uint(f);
  u += 0x7FFFu + ((u >> 16) & 1u);
  return (unsigned short)(u >> 16);
}
__device__ inline bf16x8 bc16(uint4 v) { return __builtin_bit_cast(bf16x8, v); }

#define ROWS 2176  // shorts per (z,y) row: 4 cb * 34 pos * 16 ch

__device__ inline float ucoef(int abit, int k, int jbit, float alpha) {
  if (abit == 0) return (k == 0) ? (jbit ? alpha : 1.f - alpha) : (jbit ? 1.f : 0.f);
  return (k == 2) ? (jbit ? 1.f - alpha : alpha) : (jbit ? 0.f : 1.f);
}

// ---------------- k_prep: transpose+pad / weights / combine-weights ---------
__global__ void k_prep(const float* __restrict__ x,
                       const float* __restrict__ w_def,
                       const float* __restrict__ b_def,
                       const float* __restrict__ bn1_g,
                       const float* __restrict__ bn1_b,
                       const float* __restrict__ bn1_m,
                       const float* __restrict__ bn1_v,
                       const float* __restrict__ w_comb,
                       const float* __restrict__ b_comb,
                       const float* __restrict__ bn2_g,
                       const float* __restrict__ bn2_b,
                       const float* __restrict__ bn2_m,
                       const float* __restrict__ bn2_v,
                       unsigned short* __restrict__ xTpad,
                       unsigned short* __restrict__ W_sw,
                       unsigned short* __restrict__ W2_sw,
                       float* __restrict__ bias1,
                       float* __restrict__ bias2) {
  __shared__ unsigned short t[64][65];
  int bid = blockIdx.x;
  int tid = threadIdx.x;
  if (bid < 512) {
    // transpose x [64][32768] f32 -> xTpad [1024 rows][4 cb][34 pos][16 ch]
    int s0 = bid * 64;
    int lane = tid & 63;
    int grp = tid >> 6;
    int z = s0 >> 10;
    int y0 = (s0 >> 5) & 31;
#pragma unroll
    for (int c = grp; c < 64; c += 4)
      t[c][lane] = f2bf(x[c * 32768 + s0 + lane]);
    // zero the pos-pads (pos 0 and 33, all cb) for this block's two rows
    {
      int row = tid >> 7;
      int idx = tid & 127;
      int cb = idx >> 5, side = (idx >> 4) & 1, c = idx & 15;
      xTpad[(size_t)(z * 32 + y0 + row) * ROWS + cb * 544 + side * 528 + c] = 0;
    }
    __syncthreads();
#pragma unroll
    for (int s = grp; s < 64; s += 4) {
      int row = z * 32 + y0 + (s >> 5);
      int pos = (s & 31) + 1;
      xTpad[(size_t)row * ROWS + (lane >> 4) * 544 + pos * 16 + (lane & 15)] =
          t[lane][s];
    }
  } else if (bid < 2048) {
    // phase-collapsed, BN1-folded conv weights (A-operand layout)
    int e = (bid - 512) * 256 + tid;  // < 393216
    int j = e & 7;
    int lane = (e >> 3) & 63;
    int idx = e >> 9;
    int nt = idx % 3;
    idx /= 3;
    int s = idx & 31;
    int p = idx >> 5;
    int o = lane & 31;
    int kk = 16 * s + ((lane >> 5) << 3) + j;
    int tap = kk >> 6, ch = kk & 63;
    int jz = (tap >> 2) & 1, jy = (tap >> 1) & 1, jx = tap & 1;
    int a = (p >> 2) & 1, b = (p >> 1) & 1, cp = p & 1;
    float alpha = (nt == 0) ? 0.f : ((nt == 1) ? 0.4f : 0.7f);
    const float* wb = w_def + (o * 64 + ch) * 27;
    float sum = 0.f;
    for (int kz = 0; kz < 3; ++kz) {
      float uz = ucoef(a, kz, jz, alpha);
      if (uz == 0.f) continue;
      for (int ky = 0; ky < 3; ++ky) {
        float uy = ucoef(b, ky, jy, alpha);
        if (uy == 0.f) continue;
        float uzy = uz * uy;
        for (int kx = 0; kx < 3; ++kx) {
          float ux = ucoef(cp, kx, jx, alpha);
          if (ux != 0.f) sum += wb[kz * 9 + ky * 3 + kx] * uzy * ux;
        }
      }
    }
    float s1 = bn1_g[o] * rsqrtf(bn1_v[o] + 1e-5f);
    W_sw[e] = f2bf(sum * s1);
  } else {
    // combine weights (A-operand layout) + folded biases
    for (int e = tid; e < 3072; e += 256) {
      int j = e & 7;
      int lane = (e >> 3) & 63;
      int s2 = e >> 9;
      int n = lane & 31;
      int k = 16 * s2 + ((lane >> 5) << 3) + j;
      float sc2 = bn2_g[n] * rsqrtf(bn2_v[n] + 1e-5f);
      W2_sw[e] = f2bf(w_comb[n * 96 + k] * sc2);
    }
    if (tid < 32) {
      float s1 = bn1_g[tid] * rsqrtf(bn1_v[tid] + 1e-5f);
      bias1[tid] = (b_def[tid] - bn1_m[tid]) * s1 + bn1_b[tid];
      float s2 = bn2_g[tid] * rsqrtf(bn2_v[tid] + 1e-5f);
      bias2[tid] = (b_comb[tid] - bn2_m[tid]) * s2 + bn2_b[tid];
    }
  }
}

// ---------------- k_main: LDS-weight conv GEMM + fused combine --------------
__launch_bounds__(256, 2)
__global__ void k_main(const unsigned short* __restrict__ xTpad,
                       const unsigned short* __restrict__ W_sw,
                       const unsigned short* __restrict__ W2_sw,
                       const float* __restrict__ bias1f,
                       const float* __restrict__ bias2f,
                       float* __restrict__ out) {
  __shared__ unsigned short wlds[49152];  // 48KB: 16 s-steps x 3 nt x 64 x 8
  int tid = threadIdx.x;
  int lane = tid & 63;
  int wv = tid >> 6;
  int n = lane & 31;
  int h = lane >> 5;
  int bid = blockIdx.x;
  int p = bid >> 7;            // bid = p*128 + rowGroup -> XCD = rowGroup%8
  int rowGroup = bid & 127;
  int pz = (p >> 2) & 1, py = (p >> 1) & 1, cp = p & 1;
  int r0 = rowGroup * 8 + wv * 2;  // this wave: rows r0, r0+1 (same z)
  int z = r0 >> 5, y0 = r0 & 31;

  f32x16 acc[2][3];
#pragma unroll
  for (int m = 0; m < 2; ++m)
#pragma unroll
    for (int nt = 0; nt < 3; ++nt) acc[m][nt] = (f32x16)0.f;

  const uint4* Wg = (const uint4*)W_sw + p * 6144;
  uint4* wl4 = (uint4*)wlds;

#pragma unroll
  for (int half = 0; half < 2; ++half) {
    __syncthreads();  // protect previous chunk's consumption
#pragma unroll
    for (int i = 0; i < 12; ++i) wl4[tid + i * 256] = Wg[half * 3072 + tid + i * 256];
    __syncthreads();
#pragma unroll
    for (int tt = 0; tt < 4; ++tt) {
      int t = half * 4 + tt;
      int jz = (t >> 2) & 1, jy = (t >> 1) & 1, jx = t & 1;
      int zi = z + jz - 1 + pz;
      bool zok = (unsigned)zi < 32u;
      int yi0 = y0 + jy - 1 + py;
      bool v0 = zok && (unsigned)yi0 < 32u;
      bool v1 = zok && (unsigned)(yi0 + 1) < 32u;
      const unsigned short* xb0 =
          xTpad + (size_t)(zi * 32 + yi0) * ROWS + (n + jx + cp) * 16 + 8 * h;
#pragma unroll
      for (int q = 0; q < 4; ++q) {
        const uint4* wf = wl4 + (tt * 4 + q) * 192 + lane;
        bf16x8 a0 = bc16(wf[0]);
        bf16x8 a1 = bc16(wf[64]);
        bf16x8 a2 = bc16(wf[128]);
        if (v0) {
          bf16x8 b0 = bc16(*(const uint4*)(xb0 + q * 544));
          acc[0][0] = __builtin_amdgcn_mfma_f32_32x32x16_bf16(a0, b0, acc[0][0], 0, 0, 0);
          acc[0][1] = __builtin_amdgcn_mfma_f32_32x32x16_bf16(a1, b0, acc[0][1], 0, 0, 0);
          acc[0][2] = __builtin_amdgcn_mfma_f32_32x32x16_bf16(a2, b0, acc[0][2], 0, 0, 0);
        }
        if (v1) {
          bf16x8 b1 = bc16(*(const uint4*)(xb0 + ROWS + q * 544));
          acc[1][0] = __builtin_amdgcn_mfma_f32_32x32x16_bf16(a0, b1, acc[1][0], 0, 0, 0);
          acc[1][1] = __builtin_amdgcn_mfma_f32_32x32x16_bf16(a1, b1, acc[1][1], 0, 0, 0);
          acc[1][2] = __builtin_amdgcn_mfma_f32_32x32x16_bf16(a2, b1, acc[1][2], 0, 0, 0);
        }
      }
    }
  }

  // ---- epilogue (identical math to round 3, per row m) ----------------------
  float b1r[16];
#pragma unroll
  for (int r = 0; r < 16; ++r) b1r[r] = bias1f[(r & 3) + 8 * (r >> 2) + 4 * h];
  const uint4* W24 = (const uint4*)W2_sw;

#pragma unroll
  for (int m = 0; m < 2; ++m) {
    unsigned uu[3][8];
#pragma unroll
    for (int nt = 0; nt < 3; ++nt)
#pragma unroll
      for (int i = 0; i < 8; ++i) {
        float v0 = fmaxf(acc[m][nt][2 * i] + b1r[2 * i], 0.f);
        float v1 = fmaxf(acc[m][nt][2 * i + 1] + b1r[2 * i + 1], 0.f);
        uu[nt][i] = (unsigned)f2bf(v0) | ((unsigned)f2bf(v1) << 16);
      }
    // combine GEMM: USE own quad 2e+h, SEND quad 2e+(1-h) (round-3 fix)
    f32x16 c2 = (f32x16)0.f;
#pragma unroll
    for (int s2 = 0; s2 < 6; ++s2) {
      int nt = s2 >> 1;
      int e = s2 & 1;
      int gOwn = 2 * e + h;
      int gSend = 2 * e + (1 - h);
      unsigned o0 = uu[nt][2 * gOwn], o1 = uu[nt][2 * gOwn + 1];
      unsigned s0v = uu[nt][2 * gSend], s1v = uu[nt][2 * gSend + 1];
      unsigned x0 = (unsigned)__shfl_xor((int)s0v, 32, 64);
      unsigned x1 = (unsigned)__shfl_xor((int)s1v, 32, 64);
      uint4 fv = h ? make_uint4(x0, x1, o0, o1) : make_uint4(o0, o1, x0, x1);
      bf16x8 b2 = bc16(fv);
      bf16x8 a2 = bc16(W24[s2 * 64 + lane]);
      c2 = __builtin_amdgcn_mfma_f32_32x32x16_bf16(a2, b2, c2, 0, 0, 0);
    }
    int Z = 2 * z + pz, Y = 2 * (y0 + m) + py;
    float* ob = out + Z * 4096 + Y * 64 + 2 * n + cp;
#pragma unroll
    for (int r = 0; r < 16; ++r) {
      int ch = (r & 3) + 8 * (r >> 2) + 4 * h;
      ob[(size_t)ch << 18] = fmaxf(c2[r] + bias2f[ch], 0.f);
    }
  }
}

// ---------------------------------------------------------------------------
extern "C" void kernel_launch(void* const* d_in, const int* in_sizes, int n_in,
                              void* d_out, int out_size, void* d_ws, size_t ws_size,
                              hipStream_t stream) {
  (void)in_sizes; (void)n_in; (void)out_size; (void)ws_size;
  const float* x      = (const float*)d_in[0];
  const float* w_def  = (const float*)d_in[1];
  const float* b_def  = (const float*)d_in[2];
  const float* bn1_g  = (const float*)d_in[3];
  const float* bn1_b  = (const float*)d_in[4];
  const float* bn1_m  = (const float*)d_in[5];
  const float* bn1_v  = (const float*)d_in[6];
  const float* w_comb = (const float*)d_in[7];
  const float* b_comb = (const float*)d_in[8];
  const float* bn2_g  = (const float*)d_in[9];
  const float* bn2_b  = (const float*)d_in[10];
  const float* bn2_m  = (const float*)d_in[11];
  const float* bn2_v  = (const float*)d_in[12];

  char* ws = (char*)d_ws;
  unsigned short* xTpad = (unsigned short*)(ws);            // 4,456,448 B
  unsigned short* W_sw  = (unsigned short*)(ws + 4456448);  //   786,432 B
  unsigned short* W2sw  = (unsigned short*)(ws + 5242880);  //     6,144 B
  float* bias1 = (float*)(ws + 5249024);                    //       128 B
  float* bias2 = (float*)(ws + 5249152);                    //       128 B
  float* out = (float*)d_out;

  hipLaunchKernelGGL(k_prep, dim3(2049), dim3(256), 0, stream,
                     x, w_def, b_def, bn1_g, bn1_b, bn1_m, bn1_v,
                     w_comb, b_comb, bn2_g, bn2_b, bn2_m, bn2_v,
                     xTpad, W_sw, W2sw, bias1, bias2);
  hipLaunchKernelGGL(k_main, dim3(1024), dim3(256), 0, stream,
                     xTpad, W_sw, W2sw, bias1, bias2, out);
}

// Round 5
// 174.212 us; speedup vs baseline: 1.0226x; 1.0226x over previous
//
#include <hip/hip_runtime.h>
#include <hip/hip_bf16.h>

// ---------------------------------------------------------------------------
// Round 5: r4 structure with two fixes:
//  (1) LDS bug: r4 allocated 49152 SHORTS (96KB) for a 48KB chunk -> 1
//      block/CU, 10% occupancy. Now uint4[3072] = 48KB -> 2 blocks/CU.
//  (2) m=4 rows/wave with jy-sharing: per (jx,q) step 6 ds_read_b128 +
//      5 x-loads feed 24 MFMAs (r4: 3 ds + 2 x per 6). Input rows R0..R4
//      serve taps (m,jy) via i=m+jy; only R0/R4 can be y-invalid (zero-fill,
//      MFMAs unconditional); jz validity is block-uniform (branch).
// Verified math (r3/r4, absmax 0.0625) unchanged: W_sw A-layout, x B-frags,
// fixed half-wave-shuffle combine, BN folds, store mapping, XCD grouping.
// ---------------------------------------------------------------------------

typedef __bf16 bf16x8 __attribute__((ext_vector_type(8)));
typedef float f32x16 __attribute__((ext_vector_type(16)));

__device__ inline unsigned short f2bf(float f) {
  unsigned int u = __float_as_uint(f);
  u += 0x7FFFu + ((u >> 16) & 1u);
  return (unsigned short)(u >> 16);
}
__device__ inline bf16x8 bc16(uint4 v) { return __builtin_bit_cast(bf16x8, v); }

#define ROWS 2176  // shorts per (z,y) row: 4 cb * 34 pos * 16 ch

__device__ inline float ucoef(int abit, int k, int jbit, float alpha) {
  if (abit == 0) return (k == 0) ? (jbit ? alpha : 1.f - alpha) : (jbit ? 1.f : 0.f);
  return (k == 2) ? (jbit ? 1.f - alpha : alpha) : (jbit ? 0.f : 1.f);
}

// ---------------- k_prep: transpose+pad / weights / combine-weights ---------
// (unchanged from round 4 -- verified)
__global__ void k_prep(const float* __restrict__ x,
                       const float* __restrict__ w_def,
                       const float* __restrict__ b_def,
                       const float* __restrict__ bn1_g,
                       const float* __restrict__ bn1_b,
                       const float* __restrict__ bn1_m,
                       const float* __restrict__ bn1_v,
                       const float* __restrict__ w_comb,
                       const float* __restrict__ b_comb,
                       const float* __restrict__ bn2_g,
                       const float* __restrict__ bn2_b,
                       const float* __restrict__ bn2_m,
                       const float* __restrict__ bn2_v,
                       unsigned short* __restrict__ xTpad,
                       unsigned short* __restrict__ W_sw,
                       unsigned short* __restrict__ W2_sw,
                       float* __restrict__ bias1,
                       float* __restrict__ bias2) {
  __shared__ unsigned short t[64][65];
  int bid = blockIdx.x;
  int tid = threadIdx.x;
  if (bid < 512) {
    int s0 = bid * 64;
    int lane = tid & 63;
    int grp = tid >> 6;
    int z = s0 >> 10;
    int y0 = (s0 >> 5) & 31;
#pragma unroll
    for (int c = grp; c < 64; c += 4)
      t[c][lane] = f2bf(x[c * 32768 + s0 + lane]);
    {
      int row = tid >> 7;
      int idx = tid & 127;
      int cb = idx >> 5, side = (idx >> 4) & 1, c = idx & 15;
      xTpad[(size_t)(z * 32 + y0 + row) * ROWS + cb * 544 + side * 528 + c] = 0;
    }
    __syncthreads();
#pragma unroll
    for (int s = grp; s < 64; s += 4) {
      int row = z * 32 + y0 + (s >> 5);
      int pos = (s & 31) + 1;
      xTpad[(size_t)row * ROWS + (lane >> 4) * 544 + pos * 16 + (lane & 15)] =
          t[lane][s];
    }
  } else if (bid < 2048) {
    int e = (bid - 512) * 256 + tid;  // < 393216
    int j = e & 7;
    int lane = (e >> 3) & 63;
    int idx = e >> 9;
    int nt = idx % 3;
    idx /= 3;
    int s = idx & 31;
    int p = idx >> 5;
    int o = lane & 31;
    int kk = 16 * s + ((lane >> 5) << 3) + j;
    int tap = kk >> 6, ch = kk & 63;
    int jz = (tap >> 2) & 1, jy = (tap >> 1) & 1, jx = tap & 1;
    int a = (p >> 2) & 1, b = (p >> 1) & 1, cp = p & 1;
    float alpha = (nt == 0) ? 0.f : ((nt == 1) ? 0.4f : 0.7f);
    const float* wb = w_def + (o * 64 + ch) * 27;
    float sum = 0.f;
    for (int kz = 0; kz < 3; ++kz) {
      float uz = ucoef(a, kz, jz, alpha);
      if (uz == 0.f) continue;
      for (int ky = 0; ky < 3; ++ky) {
        float uy = ucoef(b, ky, jy, alpha);
        if (uy == 0.f) continue;
        float uzy = uz * uy;
        for (int kx = 0; kx < 3; ++kx) {
          float ux = ucoef(cp, kx, jx, alpha);
          if (ux != 0.f) sum += wb[kz * 9 + ky * 3 + kx] * uzy * ux;
        }
      }
    }
    float s1 = bn1_g[o] * rsqrtf(bn1_v[o] + 1e-5f);
    W_sw[e] = f2bf(sum * s1);
  } else {
    for (int e = tid; e < 3072; e += 256) {
      int j = e & 7;
      int lane = (e >> 3) & 63;
      int s2 = e >> 9;
      int n = lane & 31;
      int k = 16 * s2 + ((lane >> 5) << 3) + j;
      float sc2 = bn2_g[n] * rsqrtf(bn2_v[n] + 1e-5f);
      W2_sw[e] = f2bf(w_comb[n * 96 + k] * sc2);
    }
    if (tid < 32) {
      float s1 = bn1_g[tid] * rsqrtf(bn1_v[tid] + 1e-5f);
      bias1[tid] = (b_def[tid] - bn1_m[tid]) * s1 + bn1_b[tid];
      float s2 = bn2_g[tid] * rsqrtf(bn2_v[tid] + 1e-5f);
      bias2[tid] = (b_comb[tid] - bn2_m[tid]) * s2 + bn2_b[tid];
    }
  }
}

// ---------------- k_main: LDS-weight conv GEMM, m=4 rows/wave ---------------
__launch_bounds__(256, 2)
__global__ void k_main(const unsigned short* __restrict__ xTpad,
                       const unsigned short* __restrict__ W_sw,
                       const unsigned short* __restrict__ W2_sw,
                       const float* __restrict__ bias1f,
                       const float* __restrict__ bias2f,
                       float* __restrict__ out) {
  __shared__ uint4 wl4[3072];  // 48 KB: one jz-chunk (taps jy,jx x 4q x 3nt)
  int tid = threadIdx.x;
  int lane = tid & 63;
  int wv = tid >> 6;
  int n = lane & 31;
  int h = lane >> 5;
  int bid = blockIdx.x;
  int p = bid >> 6;                 // XCD = (bid%8) = rowGroup%8
  int rowGroup = bid & 63;
  int pz = (p >> 2) & 1, py = (p >> 1) & 1, cp = p & 1;
  int r0 = rowGroup * 16 + wv * 4;  // wave: rows r0..r0+3 (same z)
  int z = r0 >> 5, y0 = r0 & 31;

  bool v0 = !(y0 == 0 && py == 0);   // row R0 = y0-1+py
  bool v4 = !(y0 == 28 && py == 1);  // row R4 = y0+3+py

  f32x16 acc[4][3];
#pragma unroll
  for (int m = 0; m < 4; ++m)
#pragma unroll
    for (int nt = 0; nt < 3; ++nt) acc[m][nt] = (f32x16)0.f;

  const uint4* Wg = (const uint4*)W_sw + p * 6144;
  int xoff = (n + cp) * 16 + 8 * h;  // + jx*16 later

#pragma unroll
  for (int jz = 0; jz < 2; ++jz) {
    __syncthreads();
#pragma unroll
    for (int i = 0; i < 12; ++i)
      wl4[tid + i * 256] = Wg[jz * 3072 + tid + i * 256];
    __syncthreads();
    int zi = z - 1 + pz + jz;               // block-uniform
    if ((unsigned)zi >= 32u) continue;
    const unsigned short* xb =
        xTpad + (size_t)(zi * 32 + y0 + py - 1) * ROWS;
#pragma unroll
    for (int jx = 0; jx < 2; ++jx) {
#pragma unroll
      for (int q = 0; q < 4; ++q) {
        const unsigned short* xq = xb + q * 544 + xoff + jx * 16;
        uint4 xv[5];
        xv[0] = v0 ? *(const uint4*)(xq) : make_uint4(0u, 0u, 0u, 0u);
        xv[1] = *(const uint4*)(xq + ROWS);
        xv[2] = *(const uint4*)(xq + 2 * ROWS);
        xv[3] = *(const uint4*)(xq + 3 * ROWS);
        xv[4] = v4 ? *(const uint4*)(xq + 4 * ROWS) : make_uint4(0u, 0u, 0u, 0u);
        const uint4* wf0 = wl4 + (jx * 4 + q) * 192 + lane;        // jy=0
        const uint4* wf1 = wl4 + ((2 + jx) * 4 + q) * 192 + lane;  // jy=1
        bf16x8 a00 = bc16(wf0[0]);
        bf16x8 a01 = bc16(wf0[64]);
        bf16x8 a02 = bc16(wf0[128]);
        bf16x8 a10 = bc16(wf1[0]);
        bf16x8 a11 = bc16(wf1[64]);
        bf16x8 a12 = bc16(wf1[128]);
#pragma unroll
        for (int m = 0; m < 4; ++m) {
          bf16x8 bm = bc16(xv[m]);
          bf16x8 bm1 = bc16(xv[m + 1]);
          acc[m][0] = __builtin_amdgcn_mfma_f32_32x32x16_bf16(a00, bm, acc[m][0], 0, 0, 0);
          acc[m][1] = __builtin_amdgcn_mfma_f32_32x32x16_bf16(a01, bm, acc[m][1], 0, 0, 0);
          acc[m][2] = __builtin_amdgcn_mfma_f32_32x32x16_bf16(a02, bm, acc[m][2], 0, 0, 0);
          acc[m][0] = __builtin_amdgcn_mfma_f32_32x32x16_bf16(a10, bm1, acc[m][0], 0, 0, 0);
          acc[m][1] = __builtin_amdgcn_mfma_f32_32x32x16_bf16(a11, bm1, acc[m][1], 0, 0, 0);
          acc[m][2] = __builtin_amdgcn_mfma_f32_32x32x16_bf16(a12, bm1, acc[m][2], 0, 0, 0);
        }
      }
    }
  }

  // ---- epilogue (identical math to round 3/4, per row m) --------------------
  float b1r[16];
#pragma unroll
  for (int r = 0; r < 16; ++r) b1r[r] = bias1f[(r & 3) + 8 * (r >> 2) + 4 * h];
  const uint4* W24 = (const uint4*)W2_sw;

#pragma unroll
  for (int m = 0; m < 4; ++m) {
    unsigned uu[3][8];
#pragma unroll
    for (int nt = 0; nt < 3; ++nt)
#pragma unroll
      for (int i = 0; i < 8; ++i) {
        float q0 = fmaxf(acc[m][nt][2 * i] + b1r[2 * i], 0.f);
        float q1 = fmaxf(acc[m][nt][2 * i + 1] + b1r[2 * i + 1], 0.f);
        uu[nt][i] = (unsigned)f2bf(q0) | ((unsigned)f2bf(q1) << 16);
      }
    // combine GEMM: USE own quad 2e+h, SEND quad 2e+(1-h) (round-3 fix)
    f32x16 c2 = (f32x16)0.f;
#pragma unroll
    for (int s2 = 0; s2 < 6; ++s2) {
      int nt = s2 >> 1;
      int e = s2 & 1;
      int gOwn = 2 * e + h;
      int gSend = 2 * e + (1 - h);
      unsigned o0 = uu[nt][2 * gOwn], o1 = uu[nt][2 * gOwn + 1];
      unsigned s0v = uu[nt][2 * gSend], s1v = uu[nt][2 * gSend + 1];
      unsigned x0 = (unsigned)__shfl_xor((int)s0v, 32, 64);
      unsigned x1 = (unsigned)__shfl_xor((int)s1v, 32, 64);
      uint4 fv = h ? make_uint4(x0, x1, o0, o1) : make_uint4(o0, o1, x0, x1);
      bf16x8 b2 = bc16(fv);
      bf16x8 a2 = bc16(W24[s2 * 64 + lane]);
      c2 = __builtin_amdgcn_mfma_f32_32x32x16_bf16(a2, b2, c2, 0, 0, 0);
    }
    int Z = 2 * z + pz, Y = 2 * (y0 + m) + py;
    float* ob = out + Z * 4096 + Y * 64 + 2 * n + cp;
#pragma unroll
    for (int r = 0; r < 16; ++r) {
      int ch = (r & 3) + 8 * (r >> 2) + 4 * h;
      ob[(size_t)ch << 18] = fmaxf(c2[r] + bias2f[ch], 0.f);
    }
  }
}

// ---------------------------------------------------------------------------
extern "C" void kernel_launch(void* const* d_in, const int* in_sizes, int n_in,
                              void* d_out, int out_size, void* d_ws, size_t ws_size,
                              hipStream_t stream) {
  (void)in_sizes; (void)n_in; (void)out_size; (void)ws_size;
  const float* x      = (const float*)d_in[0];
  const float* w_def  = (const float*)d_in[1];
  const float* b_def  = (const float*)d_in[2];
  const float* bn1_g  = (const float*)d_in[3];
  const float* bn1_b  = (const float*)d_in[4];
  const float* bn1_m  = (const float*)d_in[5];
  const float* bn1_v  = (const float*)d_in[6];
  const float* w_comb = (const float*)d_in[7];
  const float* b_comb = (const float*)d_in[8];
  const float* bn2_g  = (const float*)d_in[9];
  const float* bn2_b  = (const float*)d_in[10];
  const float* bn2_m  = (const float*)d_in[11];
  const float* bn2_v  = (const float*)d_in[12];

  char* ws = (char*)d_ws;
  unsigned short* xTpad = (unsigned short*)(ws);            // 4,456,448 B
  unsigned short* W_sw  = (unsigned short*)(ws + 4456448);  //   786,432 B
  unsigned short* W2sw  = (unsigned short*)(ws + 5242880);  //     6,144 B
  float* bias1 = (float*)(ws + 5249024);                    //       128 B
  float* bias2 = (float*)(ws + 5249152);                    //       128 B
  float* out = (float*)d_out;

  hipLaunchKernelGGL(k_prep, dim3(2049), dim3(256), 0, stream,
                     x, w_def, b_def, bn1_g, bn1_b, bn1_m, bn1_v,
                     w_comb, b_comb, bn2_g, bn2_b, bn2_m, bn2_v,
                     xTpad, W_sw, W2sw, bias1, bias2);
  hipLaunchKernelGGL(k_main, dim3(512), dim3(256), 0, stream,
                     xTpad, W_sw, W2sw, bias1, bias2, out);
}

// Round 6
// 168.905 us; speedup vs baseline: 1.0547x; 1.0314x over previous
//
#include <hip/hip_runtime.h>
#include <hip/hip_bf16.h>

// ---------------------------------------------------------------------------
// Round 6: full-line writes by construction.
//  * Block = 4 waves: (wv>>1) selects row quad (r0..r3 / r4..r7), (wv&1) = cp.
//    Block owns complete 64-float X lines -> epilogue stages c2 in LDS and
//    writes float4 FULL lines (r5's 60.6MB WRITE_SIZE was stride-2 half-line
//    writes missing L2 merge; this makes merging unnecessary).
//  * Weights staged per (jz,jy): 2 taps x 4q x 3nt x 64 x 16B x 2cp = 48KB.
//  * x loads direct from global (L2-hot; per-XCD working set ~2MB).
//  * Epilogue obuf (32KB) reuses the weight LDS after last stage.
// Verified math (r3-r5, absmax 0.0625) unchanged: W_sw A-layout, x B-frags,
// half-wave-shuffle combine (own quad 2e+h, send 2e+(1-h)), BN folds.
// ---------------------------------------------------------------------------

typedef __bf16 bf16x8 __attribute__((ext_vector_type(8)));
typedef float f32x16 __attribute__((ext_vector_type(16)));

__device__ inline unsigned short f2bf(float f) {
  unsigned int u = __float_as_uint(f);
  u += 0x7FFFu + ((u >> 16) & 1u);
  return (unsigned short)(u >> 16);
}
__device__ inline bf16x8 bc16(uint4 v) { return __builtin_bit_cast(bf16x8, v); }

#define ROWS 2176  // shorts per (z,y) row: 4 cb * 34 pos * 16 ch

__device__ inline float ucoef(int abit, int k, int jbit, float alpha) {
  if (abit == 0) return (k == 0) ? (jbit ? alpha : 1.f - alpha) : (jbit ? 1.f : 0.f);
  return (k == 2) ? (jbit ? 1.f - alpha : alpha) : (jbit ? 0.f : 1.f);
}

// ---------------- k_prep ----------------------------------------------------
__global__ void k_prep(const float* __restrict__ x,
                       const float* __restrict__ w_def,
                       const float* __restrict__ b_def,
                       const float* __restrict__ bn1_g,
                       const float* __restrict__ bn1_b,
                       const float* __restrict__ bn1_m,
                       const float* __restrict__ bn1_v,
                       const float* __restrict__ w_comb,
                       const float* __restrict__ b_comb,
                       const float* __restrict__ bn2_g,
                       const float* __restrict__ bn2_b,
                       const float* __restrict__ bn2_m,
                       const float* __restrict__ bn2_v,
                       unsigned short* __restrict__ xTpad,
                       unsigned short* __restrict__ W_sw,
                       unsigned short* __restrict__ W2_sw,
                       float* __restrict__ bias1,
                       float* __restrict__ bias2) {
  __shared__ unsigned short t[64][65];
  int bid = blockIdx.x;
  int tid = threadIdx.x;
  if (bid < 512) {
    // transpose x [64][32768] f32 -> xTpad [1024 rows][4 cb][34 pos][16 ch]
    int s0 = bid * 64;
    int lane = tid & 63;
    int grp = tid >> 6;
    int z = s0 >> 10;
    int y0 = (s0 >> 5) & 31;
#pragma unroll
    for (int c = grp; c < 64; c += 4)
      t[c][lane] = f2bf(x[c * 32768 + s0 + lane]);
    {  // zero the pos-pads (pos 0 and 33, all cb) for this block's two rows
      int row = tid >> 7;
      int idx = tid & 127;
      int cb = idx >> 5, side = (idx >> 4) & 1, c = idx & 15;
      xTpad[(size_t)(z * 32 + y0 + row) * ROWS + cb * 544 + side * 528 + c] = 0;
    }
    __syncthreads();
    // contiguous 32B-chunk write-out (full lines)
    {
      int row = tid >> 7, cb = (tid >> 5) & 3, seg = tid & 31;
      int s = row * 32 + seg;
      unsigned v[8];
#pragma unroll
      for (int i = 0; i < 8; ++i)
        v[i] = (unsigned)t[cb * 16 + 2 * i][s] |
               ((unsigned)t[cb * 16 + 2 * i + 1][s] << 16);
      unsigned short* dst = xTpad + (size_t)(z * 32 + y0 + row) * ROWS +
                            cb * 544 + (seg + 1) * 16;
      *(uint4*)dst = make_uint4(v[0], v[1], v[2], v[3]);
      *(uint4*)(dst + 8) = make_uint4(v[4], v[5], v[6], v[7]);
    }
  } else if (bid < 576) {
    // phase-collapsed BN1-folded conv weights: thread = (p, o, ch)
    int t0 = (bid - 512) * 256 + tid;  // [0, 16384)
    int p = t0 >> 11;
    int o = (t0 >> 6) & 31;
    int ch = t0 & 63;
    int a = (p >> 2) & 1, b = (p >> 1) & 1, cp = p & 1;
    float w[27];
    const float* wb = w_def + (o * 64 + ch) * 27;
#pragma unroll
    for (int i = 0; i < 27; ++i) w[i] = wb[i];
    float s1o = bn1_g[o] * rsqrtf(bn1_v[o] + 1e-5f);
    int lane = ((ch >> 3) & 1) * 32 + o;
    int j = ch & 7;
#pragma unroll
    for (int nt = 0; nt < 3; ++nt) {
      float alpha = (nt == 0) ? 0.f : ((nt == 1) ? 0.4f : 0.7f);
#pragma unroll
      for (int tap = 0; tap < 8; ++tap) {
        int jz = (tap >> 2) & 1, jy = (tap >> 1) & 1, jx = tap & 1;
        float sum = 0.f;
        for (int kz = 0; kz < 3; ++kz) {
          float uz = ucoef(a, kz, jz, alpha);
          if (uz == 0.f) continue;
          for (int ky = 0; ky < 3; ++ky) {
            float uy = ucoef(b, ky, jy, alpha);
            if (uy == 0.f) continue;
            float uzy = uz * uy;
            for (int kx = 0; kx < 3; ++kx) {
              float ux = ucoef(cp, kx, jx, alpha);
              if (ux != 0.f) sum += w[kz * 9 + ky * 3 + kx] * uzy * ux;
            }
          }
        }
        int s = tap * 4 + (ch >> 4);
        int e = ((p * 32 + s) * 3 + nt) * 512 + lane * 8 + j;
        W_sw[e] = f2bf(sum * s1o);
      }
    }
  } else {
    // combine weights (A-operand layout) + folded biases
    for (int e = tid; e < 3072; e += 256) {
      int j = e & 7;
      int lane = (e >> 3) & 63;
      int s2 = e >> 9;
      int n = lane & 31;
      int k = 16 * s2 + ((lane >> 5) << 3) + j;
      float sc2 = bn2_g[n] * rsqrtf(bn2_v[n] + 1e-5f);
      W2_sw[e] = f2bf(w_comb[n * 96 + k] * sc2);
    }
    if (tid < 32) {
      float s1 = bn1_g[tid] * rsqrtf(bn1_v[tid] + 1e-5f);
      bias1[tid] = (b_def[tid] - bn1_m[tid]) * s1 + bn1_b[tid];
      float s2 = bn2_g[tid] * rsqrtf(bn2_v[tid] + 1e-5f);
      bias2[tid] = (b_comb[tid] - bn2_m[tid]) * s2 + bn2_b[tid];
    }
  }
}

// ---------------- k_main: both-cp block, full-line stores -------------------
__launch_bounds__(256, 2)
__global__ void k_main(const unsigned short* __restrict__ xTpad,
                       const unsigned short* __restrict__ W_sw,
                       const unsigned short* __restrict__ W2_sw,
                       const float* __restrict__ bias1f,
                       const float* __restrict__ bias2f,
                       float* __restrict__ out) {
  __shared__ uint4 smem[3072];  // 48KB: weights per (jz,jy) x 2cp; then obuf
  int tid = threadIdx.x;
  int lane = tid & 63;
  int wv = tid >> 6;
  int n = lane & 31;
  int h = lane >> 5;
  int p2 = wv >> 1;   // row quad
  int cp = wv & 1;    // X parity phase
  int bid = blockIdx.x;
  int pp = bid >> 7;            // (pz,py); XCD = bid%8 = rg%8
  int rg = bid & 127;
  int pz = pp >> 1, py = pp & 1;
  int rbase = rg * 8 + p2 * 4;  // wave rows rbase..rbase+3, one z-slice
  int z = rbase >> 5, y0 = rbase & 31;

  f32x16 acc[4][3];
#pragma unroll
  for (int m = 0; m < 4; ++m)
#pragma unroll
    for (int nt = 0; nt < 3; ++nt) acc[m][nt] = (f32x16)0.f;

  const uint4* Wg = (const uint4*)W_sw;
  int pbase0 = (pp * 2) * 6144;      // cp=0 phase weight base (uint4)
  int xoff = (n + cp) * 16 + 8 * h;  // +jx*16 later

#pragma unroll
  for (int st = 0; st < 4; ++st) {
    int jz = st >> 1, jy = st & 1;
    int chunk = (jz * 4 + jy * 2) * 768;  // 1536 uint4 per phase
    __syncthreads();
#pragma unroll
    for (int i = 0; i < 12; ++i) {
      int idx = tid + i * 256;  // [0,3072)
      int cpi = idx >> 11 ? 1 : 0;          // idx>=1536 ?  (3072/2)
      cpi = (idx >= 1536);
      int off = idx - cpi * 1536;
      smem[idx] = Wg[pbase0 + cpi * 6144 + chunk + off];
    }
    __syncthreads();
    int zi = z + pz + jz - 1;  // block-uniform
    if ((unsigned)zi < 32u) {
      int ybase = y0 + py - 1 + jy;
      const unsigned short* xb[4];
      bool vm[4];
#pragma unroll
      for (int m = 0; m < 4; ++m) {
        int yi = ybase + m;
        vm[m] = (unsigned)yi < 32u;
        int yc = vm[m] ? yi : 0;
        xb[m] = xTpad + (size_t)(zi * 32 + yc) * ROWS + xoff;
      }
      const uint4* wbase = smem + cp * 1536;
#pragma unroll
      for (int jx = 0; jx < 2; ++jx) {
#pragma unroll
        for (int q = 0; q < 4; ++q) {
          int xo = q * 544 + jx * 16;
          uint4 xv[4];
#pragma unroll
          for (int m = 0; m < 4; ++m)
            xv[m] = vm[m] ? *(const uint4*)(xb[m] + xo)
                          : make_uint4(0u, 0u, 0u, 0u);
          const uint4* wf = wbase + jx * 768 + q * 192 + lane;
          bf16x8 a0 = bc16(wf[0]);
          bf16x8 a1 = bc16(wf[64]);
          bf16x8 a2 = bc16(wf[128]);
#pragma unroll
          for (int m = 0; m < 4; ++m) {
            bf16x8 bm = bc16(xv[m]);
            acc[m][0] = __builtin_amdgcn_mfma_f32_32x32x16_bf16(a0, bm, acc[m][0], 0, 0, 0);
            acc[m][1] = __builtin_amdgcn_mfma_f32_32x32x16_bf16(a1, bm, acc[m][1], 0, 0, 0);
            acc[m][2] = __builtin_amdgcn_mfma_f32_32x32x16_bf16(a2, bm, acc[m][2], 0, 0, 0);
          }
        }
      }
    }
  }

  // ---- epilogue -------------------------------------------------------------
  float b1r[16], b2r[16];
#pragma unroll
  for (int r = 0; r < 16; ++r) {
    int ch = (r & 3) + 8 * (r >> 2) + 4 * h;
    b1r[r] = bias1f[ch];
    b2r[r] = bias2f[ch];
  }
  const uint4* W24 = (const uint4*)W2_sw;
  float* obuf = (float*)smem;  // 32KB: [rr=p2*2+mloc][32 ch][64 X]

#pragma unroll
  for (int b = 0; b < 2; ++b) {
    __syncthreads();  // smem free (weights consumed / prev batch drained)
#pragma unroll
    for (int m2 = 0; m2 < 2; ++m2) {
      int m = 2 * b + m2;
      unsigned uu[3][8];
#pragma unroll
      for (int nt = 0; nt < 3; ++nt)
#pragma unroll
        for (int i = 0; i < 8; ++i) {
          float q0 = fmaxf(acc[m][nt][2 * i] + b1r[2 * i], 0.f);
          float q1 = fmaxf(acc[m][nt][2 * i + 1] + b1r[2 * i + 1], 0.f);
          uu[nt][i] = (unsigned)f2bf(q0) | ((unsigned)f2bf(q1) << 16);
        }
      // combine GEMM: USE own quad 2e+h, SEND quad 2e+(1-h) (r3-verified)
      f32x16 c2 = (f32x16)0.f;
#pragma unroll
      for (int s2 = 0; s2 < 6; ++s2) {
        int nt = s2 >> 1;
        int e = s2 & 1;
        int gOwn = 2 * e + h;
        int gSend = 2 * e + (1 - h);
        unsigned o0 = uu[nt][2 * gOwn], o1 = uu[nt][2 * gOwn + 1];
        unsigned s0v = uu[nt][2 * gSend], s1v = uu[nt][2 * gSend + 1];
        unsigned x0 = (unsigned)__shfl_xor((int)s0v, 32, 64);
        unsigned x1 = (unsigned)__shfl_xor((int)s1v, 32, 64);
        uint4 fv = h ? make_uint4(x0, x1, o0, o1) : make_uint4(o0, o1, x0, x1);
        bf16x8 b2 = bc16(fv);
        bf16x8 a2 = bc16(W24[s2 * 64 + lane]);
        c2 = __builtin_amdgcn_mfma_f32_32x32x16_bf16(a2, b2, c2, 0, 0, 0);
      }
      // stage into obuf (X-interleaved by cp)
      float* ob = obuf + ((p2 * 2 + m2) * 32) * 64 + 2 * n + cp;
#pragma unroll
      for (int r = 0; r < 16; ++r) {
        int ch = (r & 3) + 8 * (r >> 2) + 4 * h;
        ob[ch * 64] = fmaxf(c2[r] + b2r[r], 0.f);
      }
    }
    __syncthreads();
    // write out full lines: 2048 float4, 8 per thread
#pragma unroll
    for (int i = 0; i < 8; ++i) {
      int idx = tid + i * 256;       // [0,2048)
      int x4 = idx & 15;
      int ch = (idx >> 4) & 31;
      int rr = idx >> 9;             // [0,4): pair*2 + mloc
      int pr = rr >> 1, mloc = rr & 1;
      int r = rg * 8 + pr * 4 + 2 * b + mloc;
      int Z = 2 * (r >> 5) + pz, Y = 2 * (r & 31) + py;
      float4 v = *(const float4*)(obuf + (rr * 32 + ch) * 64 + x4 * 4);
      *(float4*)(out + ((size_t)ch << 18) + Z * 4096 + Y * 64 + x4 * 4) = v;
    }
  }
}

// ---------------------------------------------------------------------------
extern "C" void kernel_launch(void* const* d_in, const int* in_sizes, int n_in,
                              void* d_out, int out_size, void* d_ws, size_t ws_size,
                              hipStream_t stream) {
  (void)in_sizes; (void)n_in; (void)out_size; (void)ws_size;
  const float* x      = (const float*)d_in[0];
  const float* w_def  = (const float*)d_in[1];
  const float* b_def  = (const float*)d_in[2];
  const float* bn1_g  = (const float*)d_in[3];
  const float* bn1_b  = (const float*)d_in[4];
  const float* bn1_m  = (const float*)d_in[5];
  const float* bn1_v  = (const float*)d_in[6];
  const float* w_comb = (const float*)d_in[7];
  const float* b_comb = (const float*)d_in[8];
  const float* bn2_g  = (const float*)d_in[9];
  const float* bn2_b  = (const float*)d_in[10];
  const float* bn2_m  = (const float*)d_in[11];
  const float* bn2_v  = (const float*)d_in[12];

  char* ws = (char*)d_ws;
  unsigned short* xTpad = (unsigned short*)(ws);            // 4,456,448 B
  unsigned short* W_sw  = (unsigned short*)(ws + 4456448);  //   786,432 B
  unsigned short* W2sw  = (unsigned short*)(ws + 5242880);  //     6,144 B
  float* bias1 = (float*)(ws + 5249024);                    //       128 B
  float* bias2 = (float*)(ws + 5249152);                    //       128 B
  float* out = (float*)d_out;

  hipLaunchKernelGGL(k_prep, dim3(577), dim3(256), 0, stream,
                     x, w_def, b_def, bn1_g, bn1_b, bn1_m, bn1_v,
                     w_comb, b_comb, bn2_g, bn2_b, bn2_m, bn2_v,
                     xTpad, W_sw, W2sw, bias1, bias2);
  hipLaunchKernelGGL(k_main, dim3(512), dim3(256), 0, stream,
                     xTpad, W_sw, W2sw, bias1, bias2, out);
}